// Round 6
// baseline (385.721 us; speedup 1.0000x reference)
//
#include <hip/hip_runtime.h>
#include <hip/hip_bf16.h>

typedef __attribute__((ext_vector_type(4))) float f32x4;
typedef __attribute__((ext_vector_type(8))) short short8;

static constexpr int BB = 32;
static constexpr int SEQ = 1024;
static constexpr int DIM = 1024;

__device__ __forceinline__ ushort f2bf(float f) {
  union { float f; uint u; } x; x.f = f;
  uint r = x.u + 0x7fffu + ((x.u >> 16) & 1u);
  return (ushort)(r >> 16);
}
__device__ __forceinline__ float bf2f(ushort h) {
  union { uint u; float f; } x; x.u = ((uint)h) << 16; return x.f;
}

// async global->LDS, 16B per lane (dest = wave-uniform base + lane*16).
__device__ __forceinline__ void async16(const void* g, void* l) {
  __builtin_amdgcn_global_load_lds(
      (const __attribute__((address_space(1))) unsigned int*)g,
      (__attribute__((address_space(3))) unsigned int*)l, 16, 0, 0);
}

// fp32 -> bf16 elementwise (vectorized by 4)
__global__ void cvt_kernel(const float* __restrict__ in, ushort* __restrict__ out, long n4) {
  long i = (long)blockIdx.x * blockDim.x + threadIdx.x;
  const long stride = (long)gridDim.x * blockDim.x;
  for (; i < n4; i += stride) {
    float4 v = reinterpret_cast<const float4*>(in)[i];
    ushort4 o = make_ushort4(f2bf(v.x), f2bf(v.y), f2bf(v.z), f2bf(v.w));
    reinterpret_cast<ushort4*>(out)[i] = o;
  }
}

// ---------------------------------------------------------------------------
// 128x128-tile, BK=32, 4-wave (2x2, 64x64/wave) 2-phase GEMM (m97 structure).
// TLP-first: 32KB LDS -> 4-5 blocks/CU; cross-block overlap hides the
// per-K-step barrier drain (m114). Linear LDS (conflicts timing-null at
// 2-phase, m252). 1-D grid with XCD-chunked remap (T1): hardware assigns
// xcd = bid%8, so logical = (bid%8)*(nwg/8) + bid/8 gives each XCD a
// CONTIGUOUS logical range -> co-resident blocks share A/B panels in L2.
// Logical id decomposes x-fastest (same-A-panel blocks adjacent).
// C[m,n] = scale * sum_k A[m,k]*Bt[n,k] (+ bias[n]); A:[M][K] Bt:[N][K] bf16.
// TMODE=1: also write transposed bf16 to Tout[row>>10][col][row&1023].
// SYM=1 (square, A==Bt, per-batch): grid enumerates lower-triangle tile
// pairs (ty>=tx); off-diagonal tiles mirror-write C[z][col][row] (bitwise
// exact: per-k products commute, accumulation order identical).
// ---------------------------------------------------------------------------
template<int OUT_BF16, int HAS_BIAS, int TMODE, int SYM>
__global__ void gemm_bt(const ushort* __restrict__ A, const ushort* __restrict__ Bt,
                        void* __restrict__ Cv, const float* __restrict__ bias,
                        ushort* __restrict__ Tout,
                        int nx, int ny, int K, float scale,
                        long sA, long sB, long sC)
{
  __shared__ ushort As[2][128 * 32];
  __shared__ ushort Bs[2][128 * 32];

  // XCD-chunked remap (grid divisible by 8)
  const int lg = (blockIdx.x & 7) * (gridDim.x >> 3) + (blockIdx.x >> 3);
  int tx, ty, z;
  if (SYM) {
    const int P = nx * (nx + 1) / 2;
    z = lg / P;
    const int u = lg - z * P;
    int i = 0;
    while ((i + 1) * (i + 2) / 2 <= u) ++i;
    ty = i; tx = u - i * (i + 1) / 2;       // ty >= tx
  } else {
    tx = lg % nx;
    const int r = lg / nx;
    ty = r % ny;
    z = r / ny;
  }
  const int N = nx * 128;
  const int tm = ty * 128;
  const int tn = tx * 128;

  const ushort* Ab = A + (long)z * sA;
  const ushort* Bb = Bt + (long)z * sB;

  const int t = threadIdx.x;
  const int l  = t & 63;
  const int w  = t >> 6;
  const int wm = (w >> 1) * 64;
  const int wn = (w & 1) * 64;
  const int fr = l & 15;        // row-in-frag (A) / col-in-frag (B,C)
  const int ke = (l >> 4) * 8;  // k element offset within BK for frag load

  f32x4 acc[4][4];
#pragma unroll
  for (int i = 0; i < 4; ++i)
#pragma unroll
    for (int j = 0; j < 4; ++j) acc[i][j] = {0.f, 0.f, 0.f, 0.f};

  auto stage = [&](int buf, int k0) {
#pragma unroll
    for (int it = 0; it < 2; ++it) {
      const int idx = t + it * 256;        // 0..511 -> LDS byte idx*16 (thread-linear)
      const int r   = idx >> 2;            // 0..127 tile row
      const int kb  = (idx & 3) * 8;       // 0,8,16,24 elems
      async16(Ab + (long)(tm + r) * K + (k0 + kb), &As[buf][idx * 8]);
      async16(Bb + (long)(tn + r) * K + (k0 + kb), &Bs[buf][idx * 8]);
    }
  };

  const int nk = K >> 5;
  stage(0, 0);
  __syncthreads();
  for (int kt = 0; kt < nk; ++kt) {
    const int buf = kt & 1;
    if (kt + 1 < nk) stage(buf ^ 1, (kt + 1) << 5);
    short8 af[4], bfr[4];
#pragma unroll
    for (int f = 0; f < 4; ++f) {
      af[f]  = *(const short8*)&As[buf][(wm + f * 16 + fr) * 32 + ke];
      bfr[f] = *(const short8*)&Bs[buf][(wn + f * 16 + fr) * 32 + ke];
    }
#pragma unroll
    for (int i = 0; i < 4; ++i)
#pragma unroll
      for (int j = 0; j < 4; ++j)
        acc[i][j] = __builtin_amdgcn_mfma_f32_16x16x32_bf16(af[i], bfr[j], acc[i][j], 0, 0, 0);
    __syncthreads();
  }

  // epilogue: C/D layout col=lane&15, row=(lane>>4)*4+reg  [verified m89/m91]
  const int cr = (l >> 4) * 4;
#pragma unroll
  for (int i = 0; i < 4; ++i) {
#pragma unroll
    for (int j = 0; j < 4; ++j) {
      const int row = tm + wm + i * 16 + cr;
      const int col = tn + wn + j * 16 + fr;
      const float bv = HAS_BIAS ? bias[col] : 0.0f;
      float v[4];
#pragma unroll
      for (int r = 0; r < 4; ++r) v[r] = acc[i][j][r] * scale + bv;
#pragma unroll
      for (int r = 0; r < 4; ++r) {
        const long off = (long)z * sC + (long)(row + r) * N + col;
        if (OUT_BF16) ((ushort*)Cv)[off] = f2bf(v[r]);
        else          ((float*)Cv)[off]  = v[r];
      }
      if (TMODE) {  // transposed copy: Tout[row>>10][col][row&1023..+3]
        ushort4 o = make_ushort4(f2bf(v[0]), f2bf(v[1]), f2bf(v[2]), f2bf(v[3]));
        const long ti = ((long)(row >> 10) << 20) + ((long)col << 10) + (row & 1023);
        *(ushort4*)&Tout[ti] = o;
      }
      if (SYM && tx != ty) {  // mirror tile: C[z][col][row..row+3] (bitwise exact)
        ushort4 o = make_ushort4(f2bf(v[0]), f2bf(v[1]), f2bf(v[2]), f2bf(v[3]));
        *(ushort4*)((ushort*)Cv + (long)z * sC + (long)col * N + row) = o;
      }
    }
  }
}

// softmax over BATCH dim (axis=0): for each (q,k), normalize across 32 batches.
__global__ void softmax_b(ushort* __restrict__ sc) {
  const long SSl = (long)SEQ * SEQ;
  const long e = ((long)blockIdx.x * blockDim.x + threadIdx.x) * 4;
  if (e >= SSl) return;
  uint2 raw[BB];
#pragma unroll
  for (int b = 0; b < BB; ++b) raw[b] = *(const uint2*)&sc[b * SSl + e];
  float mx[4] = {-3.0e38f, -3.0e38f, -3.0e38f, -3.0e38f};
#pragma unroll
  for (int b = 0; b < BB; ++b) {
    const uint lo = raw[b].x, hi = raw[b].y;
    mx[0] = fmaxf(mx[0], bf2f((ushort)(lo & 0xffffu)));
    mx[1] = fmaxf(mx[1], bf2f((ushort)(lo >> 16)));
    mx[2] = fmaxf(mx[2], bf2f((ushort)(hi & 0xffffu)));
    mx[3] = fmaxf(mx[3], bf2f((ushort)(hi >> 16)));
  }
  float sum[4] = {0.f, 0.f, 0.f, 0.f};
#pragma unroll
  for (int b = 0; b < BB; ++b) {
    const uint lo = raw[b].x, hi = raw[b].y;
    const float x0 = __expf(bf2f((ushort)(lo & 0xffffu)) - mx[0]);
    const float x1 = __expf(bf2f((ushort)(lo >> 16))     - mx[1]);
    const float x2 = __expf(bf2f((ushort)(hi & 0xffffu)) - mx[2]);
    const float x3 = __expf(bf2f((ushort)(hi >> 16))     - mx[3]);
    sum[0] += x0; sum[1] += x1; sum[2] += x2; sum[3] += x3;
    raw[b].x = (uint)f2bf(x0) | ((uint)f2bf(x1) << 16);
    raw[b].y = (uint)f2bf(x2) | ((uint)f2bf(x3) << 16);
  }
  const float r0 = 1.0f / sum[0], r1 = 1.0f / sum[1];
  const float r2 = 1.0f / sum[2], r3 = 1.0f / sum[3];
#pragma unroll
  for (int b = 0; b < BB; ++b) {
    const uint lo = raw[b].x, hi = raw[b].y;
    const uint o0 = f2bf(bf2f((ushort)(lo & 0xffffu)) * r0);
    const uint o1 = f2bf(bf2f((ushort)(lo >> 16))     * r1);
    const uint o2 = f2bf(bf2f((ushort)(hi & 0xffffu)) * r2);
    const uint o3 = f2bf(bf2f((ushort)(hi >> 16))     * r3);
    uint2 o; o.x = o0 | (o1 << 16); o.y = o2 | (o3 << 16);
    *(uint2*)&sc[b * SSl + e] = o;
  }
}

extern "C" void kernel_launch(void* const* d_in, const int* in_sizes, int n_in,
                              void* d_out, int out_size, void* d_ws, size_t ws_size,
                              hipStream_t stream) {
  const float* text = (const float*)d_in[0];
  const float* W    = (const float*)d_in[1];
  const float* bias = (const float*)d_in[2];
  float* out = (float*)d_out;

  const long nTxt = (long)BB * SEQ * DIM;   // 33,554,432
  const long nW   = (long)DIM * DIM;        // 1,048,576
  const long SSl  = (long)SEQ * SEQ;        // per-batch score elems

  char* ws = (char*)d_ws;
  ushort* qkv   = (ushort*)ws;                 // 64MB bf16 qkv [B][S][D]
  ushort* qkvT  = (ushort*)(ws + nTxt * 2);    // 64MB bf16 qkv^T [B][D][S]
  ushort* sc    = (ushort*)(ws + nTxt * 4);    // 64MB: text_bf16, then scores/attn
  ushort* textb = sc;                          // alias (text_bf16 dead after GEMM1)
  ushort* Wb    = (ushort*)(ws + nTxt * 6);    // 2MB bf16 W [D][D]
  if (ws_size < (size_t)(nTxt * 6 + nW * 2)) return;  // insufficient scratch

  // 1. convert inputs to bf16
  cvt_kernel<<<2048, 256, 0, stream>>>(text, textb, nTxt / 4);
  cvt_kernel<<<256, 256, 0, stream>>>(W, Wb, nW / 4);
  // 2. qkv = text @ W.T + b  (M=32768,N=1024,K=1024); fused qkvT write
  gemm_bt<1, 1, 1, 0><<<2048, 256, 0, stream>>>(
      textb, Wb, qkv, bias, qkvT, 8, 256, DIM, 1.0f, 0, 0, 0);
  // 3. scores[b] = qkv[b] @ qkv[b]^T / sqrt(D), symmetric: 36/64 tiles + mirror
  gemm_bt<1, 0, 0, 1><<<1152, 256, 0, stream>>>(
      qkv, qkv, sc, nullptr, nullptr, 8, 8, DIM, 0.03125f, SSl, SSl, SSl);
  // 4. softmax over batch dim (in-place)
  softmax_b<<<1024, 256, 0, stream>>>(sc);
  // 5. out[b] = attn[b] @ qkv[b]  (B operand via qkvT), fp32 out
  gemm_bt<0, 0, 0, 0><<<2048, 256, 0, stream>>>(
      sc, qkvT, out, nullptr, nullptr, 8, 8, SEQ, 1.0f, SSl, SSl, SSl);
}